// Round 2
// baseline (233.893 us; speedup 1.0000x reference)
//
#include <hip/hip_runtime.h>

// PositionalEncoder: out[k] = sum_j ((1 - j/J) - (k/d)*(1 - 2j/J)) * E[j,k]
// j = 1..J (row+1), k = 1..d (col+1). E row-major [J, D] fp32.
// Memory-bound: 128 MiB read once -> ~21 us HBM floor (kernel-side).
// R2: fused single-pass with device-scope float atomics into d_out
// (replaces 4 MiB ws round-trip + 8-block stage2). d_out is poisoned 0xAA
// by the harness each call -> explicit zero kernel first (same stream).

constexpr int D_COLS = 2048;
constexpr int J_ROWS = 16384;
constexpr int T1 = 512;   // threads/block: 512 x float4 spans one full row
constexpr int NB = 512;   // blocks: 16384/512 = 32 rows/block, 16 waves/CU

__global__ __launch_bounds__(T1) void pe_zero(float* __restrict__ out) {
    // 512 threads x float4 = 2048 floats = whole output
    *reinterpret_cast<float4*>(out + threadIdx.x * 4) =
        make_float4(0.f, 0.f, 0.f, 0.f);
}

__global__ __launch_bounds__(T1) void pe_fused(const float* __restrict__ E,
                                               float* __restrict__ out) {
    const int tid  = threadIdx.x;
    const int col0 = tid * 4;
    const float invJ = 1.0f / (float)J_ROWS;
    const float invD = 1.0f / (float)D_COLS;
    // c_k = k/d for this thread's 4 columns (k = col+1) — loop-invariant
    const float c0 = (float)(col0 + 1) * invD;
    const float c1 = (float)(col0 + 2) * invD;
    const float c2 = (float)(col0 + 3) * invD;
    const float c3 = (float)(col0 + 4) * invD;

    float4 acc = make_float4(0.f, 0.f, 0.f, 0.f);
    // 32 rows per block, unrolled x2: two independent float4 loads in flight.
    // J_ROWS % (2*NB) == 0, so no tail guard needed.
    for (int row = blockIdx.x; row < J_ROWS; row += 2 * NB) {
        const int r0 = row;
        const int r1 = row + NB;
        const float4 e0 = *reinterpret_cast<const float4*>(E + (size_t)r0 * D_COLS + col0);
        const float4 e1 = *reinterpret_cast<const float4*>(E + (size_t)r1 * D_COLS + col0);

        const float j0 = (float)(r0 + 1);
        const float a0 = fmaf(-j0,        invJ, 1.0f);   // 1 - j/J
        const float b0 = fmaf(-2.0f * j0, invJ, 1.0f);   // 1 - 2j/J
        const float j1 = (float)(r1 + 1);
        const float a1 = fmaf(-j1,        invJ, 1.0f);
        const float b1 = fmaf(-2.0f * j1, invJ, 1.0f);

        acc.x = fmaf(fmaf(-c0, b0, a0), e0.x, acc.x);
        acc.y = fmaf(fmaf(-c1, b0, a0), e0.y, acc.y);
        acc.z = fmaf(fmaf(-c2, b0, a0), e0.z, acc.z);
        acc.w = fmaf(fmaf(-c3, b0, a0), e0.w, acc.w);
        acc.x = fmaf(fmaf(-c0, b1, a1), e1.x, acc.x);
        acc.y = fmaf(fmaf(-c1, b1, a1), e1.y, acc.y);
        acc.z = fmaf(fmaf(-c2, b1, a1), e1.z, acc.z);
        acc.w = fmaf(fmaf(-c3, b1, a1), e1.w, acc.w);
    }

    // One block-partial per column lives in exactly one thread -> direct
    // device-scope atomic accumulate (512-way per address, addresses in
    // parallel across L2 banks).
    atomicAdd(out + col0 + 0, acc.x);
    atomicAdd(out + col0 + 1, acc.y);
    atomicAdd(out + col0 + 2, acc.z);
    atomicAdd(out + col0 + 3, acc.w);
}

extern "C" void kernel_launch(void* const* d_in, const int* in_sizes, int n_in,
                              void* d_out, int out_size, void* d_ws, size_t ws_size,
                              hipStream_t stream) {
    const float* E = (const float*)d_in[0];
    float* out = (float*)d_out;
    (void)d_ws; (void)ws_size; (void)in_sizes; (void)n_in; (void)out_size;

    pe_zero<<<1, T1, 0, stream>>>(out);
    pe_fused<<<NB, T1, 0, stream>>>(E, out);
}

// Round 3
// 199.457 us; speedup vs baseline: 1.1726x; 1.1726x over previous
//
#include <hip/hip_runtime.h>

// PositionalEncoder: out[k] = sum_j ((1 - j/J) - (k/d)*(1 - 2j/J)) * E[j,k]
// j = 1..J (row+1), k = 1..d (col+1). E row-major [J, D] fp32.
//
// R3: two-stage, atomic-free. R2's lesson: 512-deep same-address atomic
// chains cost ~70 us (WRITE_SIZE showed 16 MB of RMW traffic for an 8 KB
// output). R1's lesson: a low-parallelism strided stage2 costs ~45 us.
// Fix: stage1 writes ws TRANSPOSED (ws[col*NB + b], scatter stores are
// fire-and-forget), stage2 reduces each column's contiguous 2 KB run with
// one wave (float4 loads + shuffle butterfly) -> ~3 us.

constexpr int D_COLS = 2048;
constexpr int J_ROWS = 16384;
constexpr int T1 = 512;   // 512 threads x float4 spans one full 2048-col row
constexpr int NB = 512;   // stage-1 blocks; 32 rows/block; ws = 4 MiB

__global__ __launch_bounds__(T1) void pe_stage1(const float* __restrict__ E,
                                                float* __restrict__ ws) {
    const int tid  = threadIdx.x;
    const int col0 = tid * 4;
    const int b    = blockIdx.x;
    const float invJ = 1.0f / (float)J_ROWS;
    const float invD = 1.0f / (float)D_COLS;
    const float c0 = (float)(col0 + 1) * invD;
    const float c1 = (float)(col0 + 2) * invD;
    const float c2 = (float)(col0 + 3) * invD;
    const float c3 = (float)(col0 + 4) * invD;

    float4 acc = make_float4(0.f, 0.f, 0.f, 0.f);
    // 32 rows/block, unroll x4: 4 independent 1 KB/wave loads in flight.
    // 16384 / (4*512) = 8 iterations exactly.
    for (int row = b; row < J_ROWS; row += 4 * NB) {
        const int r0 = row, r1 = row + NB, r2 = row + 2 * NB, r3 = row + 3 * NB;
        const float4 e0 = *reinterpret_cast<const float4*>(E + (size_t)r0 * D_COLS + col0);
        const float4 e1 = *reinterpret_cast<const float4*>(E + (size_t)r1 * D_COLS + col0);
        const float4 e2 = *reinterpret_cast<const float4*>(E + (size_t)r2 * D_COLS + col0);
        const float4 e3 = *reinterpret_cast<const float4*>(E + (size_t)r3 * D_COLS + col0);

        const float j0 = (float)(r0 + 1), j1 = (float)(r1 + 1);
        const float j2 = (float)(r2 + 1), j3 = (float)(r3 + 1);
        const float a0 = fmaf(-j0, invJ, 1.0f), bb0 = fmaf(-2.f * j0, invJ, 1.0f);
        const float a1 = fmaf(-j1, invJ, 1.0f), bb1 = fmaf(-2.f * j1, invJ, 1.0f);
        const float a2 = fmaf(-j2, invJ, 1.0f), bb2 = fmaf(-2.f * j2, invJ, 1.0f);
        const float a3 = fmaf(-j3, invJ, 1.0f), bb3 = fmaf(-2.f * j3, invJ, 1.0f);

        acc.x = fmaf(fmaf(-c0, bb0, a0), e0.x, acc.x);
        acc.y = fmaf(fmaf(-c1, bb0, a0), e0.y, acc.y);
        acc.z = fmaf(fmaf(-c2, bb0, a0), e0.z, acc.z);
        acc.w = fmaf(fmaf(-c3, bb0, a0), e0.w, acc.w);
        acc.x = fmaf(fmaf(-c0, bb1, a1), e1.x, acc.x);
        acc.y = fmaf(fmaf(-c1, bb1, a1), e1.y, acc.y);
        acc.z = fmaf(fmaf(-c2, bb1, a1), e1.z, acc.z);
        acc.w = fmaf(fmaf(-c3, bb1, a1), e1.w, acc.w);
        acc.x = fmaf(fmaf(-c0, bb2, a2), e2.x, acc.x);
        acc.y = fmaf(fmaf(-c1, bb2, a2), e2.y, acc.y);
        acc.z = fmaf(fmaf(-c2, bb2, a2), e2.z, acc.z);
        acc.w = fmaf(fmaf(-c3, bb2, a2), e2.w, acc.w);
        acc.x = fmaf(fmaf(-c0, bb3, a3), e3.x, acc.x);
        acc.y = fmaf(fmaf(-c1, bb3, a3), e3.y, acc.y);
        acc.z = fmaf(fmaf(-c2, bb3, a3), e3.z, acc.z);
        acc.w = fmaf(fmaf(-c3, bb3, a3), e3.w, acc.w);
    }

    // Transposed partial store: column-major runs of NB partials.
    // Scattered 4B stores (stride 2 KB between lanes) but fire-and-forget;
    // 4 MB total, absorbed by L2/LLC. No same-address serialization.
    ws[(size_t)(col0 + 0) * NB + b] = acc.x;
    ws[(size_t)(col0 + 1) * NB + b] = acc.y;
    ws[(size_t)(col0 + 2) * NB + b] = acc.z;
    ws[(size_t)(col0 + 3) * NB + b] = acc.w;
}

// One wave per column: 512 contiguous partials = 2 KB = 64 lanes x 2 float4.
// Shuffle butterfly, lane 0 writes out[col]. 512 blocks x 4 waves.
__global__ __launch_bounds__(256) void pe_stage2(const float* __restrict__ ws,
                                                 float* __restrict__ out) {
    const int wave = threadIdx.x >> 6;
    const int lane = threadIdx.x & 63;
    const int col  = blockIdx.x * 4 + wave;
    const float4* p = reinterpret_cast<const float4*>(ws + (size_t)col * NB);
    const float4 v0 = p[lane];
    const float4 v1 = p[lane + 64];
    float s = ((v0.x + v0.y) + (v0.z + v0.w)) + ((v1.x + v1.y) + (v1.z + v1.w));
    #pragma unroll
    for (int off = 32; off > 0; off >>= 1)
        s += __shfl_down(s, off, 64);
    if (lane == 0) out[col] = s;
}

extern "C" void kernel_launch(void* const* d_in, const int* in_sizes, int n_in,
                              void* d_out, int out_size, void* d_ws, size_t ws_size,
                              hipStream_t stream) {
    const float* E = (const float*)d_in[0];
    float* out = (float*)d_out;
    float* ws = (float*)d_ws;   // needs 2048*512*4 = 4 MiB (harness gives far more)
    (void)in_sizes; (void)n_in; (void)out_size; (void)ws_size;

    pe_stage1<<<NB, T1, 0, stream>>>(E, ws);
    pe_stage2<<<D_COLS / 4, 256, 0, stream>>>(ws, out);
}